// Round 16
// baseline (118.957 us; speedup 1.0000x reference)
//
#include <hip/hip_runtime.h>
#include <math.h>

#define NN 50000
#define NE 800000
#define DD 128
#define NPAD 50048   // 782 * 64, GEMM row padding
#define NSLICE 6256  // ceil(NN/8) — dst-slice per XCD group
#define ELLW 64      // ELL row stride; P(deg>64) ~ 1e-15 for Poisson(16)
#define NBG 782      // GEMM blocks in fused kernel (NPAD/64)

typedef __attribute__((ext_vector_type(8))) short bf16x8;
typedef __attribute__((ext_vector_type(4))) float f32x4;

__device__ __forceinline__ int clampN(int v) {
  return v < 0 ? 0 : (v >= NN ? NN - 1 : v);
}

__device__ __forceinline__ unsigned short f2b(float f) {
  union { float f; unsigned int u; } x; x.f = f;
  unsigned int u = x.u;
  u += 0x7fffu + ((u >> 16) & 1u);   // round-to-nearest-even
  return (unsigned short)(u >> 16);
}

__device__ __forceinline__ float blo(unsigned int v) {
  union { unsigned int u; float f; } a; a.u = v << 16; return a.f;
}
__device__ __forceinline__ float bhi(unsigned int v) {
  union { unsigned int u; float f; } a; a.u = v & 0xffff0000u; return a.f;
}

// ---------------- prep: Wt1 transpose-to-bf16 + fused head weights ----------------

__global__ __launch_bounds__(256) void k_prep_w(
    const float* __restrict__ W1, const float* __restrict__ W2,
    const float* __restrict__ b2, const float* __restrict__ Wl,
    const float* __restrict__ bl, unsigned short* __restrict__ Wt1,
    float* __restrict__ w2l, float* __restrict__ c0b) {
  __shared__ float part[2];
  if (blockIdx.x < 64) {
    int i = blockIdx.x * 256 + threadIdx.x;   // < 16384
    int n = i >> 7, k = i & 127;
    Wt1[i] = f2b(W1[k * DD + n]);
  } else if (threadIdx.x < DD) {
    int k = threadIdx.x;
    float acc = 0.f;
    for (int c = 0; c < DD; ++c) acc += W2[k * DD + c] * Wl[c];
    w2l[k] = acc;
    float pc = b2[k] * Wl[k];
#pragma unroll
    for (int off = 32; off > 0; off >>= 1) pc += __shfl_down(pc, off, 64);
    if ((k & 63) == 0) part[k >> 6] = pc;
    __syncthreads();
    if (k == 0) c0b[0] = part[0] + part[1] + bl[0];
  }
}

// ---------------- FUSED: GEMM (unscaled tp, LDS-FREE) + ELL scatter ----------------
// blocks [0,NBG): MFMA GEMM tile, A and B fragments straight from global
// (x read once; Wt1 32KB stays L2-hot). blocks [NBG,NBG+2048): XCD-sharded
// scatter. Zero LDS -> scatter occupancy no longer strangled (r15: 29%).

__global__ __launch_bounds__(256) void k_fused(
    const float* __restrict__ x, const unsigned short* __restrict__ Wt,
    unsigned short* __restrict__ outb,
    const int* __restrict__ ei, int* __restrict__ cur, int* __restrict__ col) {
  if (blockIdx.x >= NBG) {
    // ---- ELL scatter part ----
    int g = blockIdx.x & 7;            // physical XCD (round-robin dispatch)
    int j = blockIdx.x - NBG;          // 0..2047
    int blk = j >> 3;                  // 0..255; (g,blk) pairs cover all slices
    int lo = g * NSLICE;
    int hi = min(lo + NSLICE, NN);
    for (int i = blk * 256 + threadIdx.x; i < NE; i += 256 * 256) {
      int d = clampN(ei[NE + i]);
      if (d >= lo && d < hi) {
        int s = clampN(ei[i]);
        int pos = atomicAdd(&cur[d], 1);
        if (pos < ELLW) col[d * ELLW + pos] = s;   // cap for memory safety
      }
    }
    return;
  }

  // ---- GEMM part (no LDS, no barrier) ----
  const int tid = threadIdx.x;
  const int row0 = blockIdx.x * 64;
  const int w = tid >> 6, lane = tid & 63;
  const int lr = lane & 15, lk = lane >> 4;

  // A-fragments: row ar, 8 f32 at col k4*32 + lk*8, converted to bf16
  bf16x8 af[4];
  {
    int ar = row0 + w * 16 + lr;
    if (ar < NN) {
      const float4* xr = (const float4*)(x + (size_t)ar * DD);
#pragma unroll
      for (int k4 = 0; k4 < 4; ++k4) {
        float4 a0 = xr[k4 * 8 + lk * 2];
        float4 a1 = xr[k4 * 8 + lk * 2 + 1];
        bf16x8 v;
        v[0] = (short)f2b(a0.x); v[1] = (short)f2b(a0.y);
        v[2] = (short)f2b(a0.z); v[3] = (short)f2b(a0.w);
        v[4] = (short)f2b(a1.x); v[5] = (short)f2b(a1.y);
        v[6] = (short)f2b(a1.z); v[7] = (short)f2b(a1.w);
        af[k4] = v;
      }
    } else {
#pragma unroll
      for (int k4 = 0; k4 < 4; ++k4) af[k4] = (bf16x8){0,0,0,0,0,0,0,0};
    }
  }

  f32x4 accs[8];
#pragma unroll
  for (int n = 0; n < 8; ++n) {
    f32x4 acc = {0.f, 0.f, 0.f, 0.f};
    int br = n * 16 + lr;
    const unsigned short* wr = Wt + (size_t)br * DD + lk * 8;
#pragma unroll
    for (int k4 = 0; k4 < 4; ++k4) {
      bf16x8 bf = *(const bf16x8*)(wr + k4 * 32);   // L2-hot
      acc = __builtin_amdgcn_mfma_f32_16x16x32_bf16(af[k4], bf, acc, 0, 0, 0);
    }
    accs[n] = acc;
  }

#pragma unroll
  for (int r = 0; r < 4; ++r) {
    int grow = row0 + w * 16 + lk * 4 + r;
    if (grow < NN) {
#pragma unroll
      for (int n = 0; n < 8; ++n)
        outb[(size_t)grow * DD + n * 16 + lr] = f2b(accs[n][r]);  // UNSCALED
    }
  }
}

// ---------------- Layer-1 aggregate + relu + w2l projection (ELL, inline dinv) ----

__device__ __forceinline__ void acc8m(float* acc, uint4 v, float m) {
  acc[0] = fmaf(m, blo(v.x), acc[0]);
  acc[1] = fmaf(m, bhi(v.x), acc[1]);
  acc[2] = fmaf(m, blo(v.y), acc[2]);
  acc[3] = fmaf(m, bhi(v.y), acc[3]);
  acc[4] = fmaf(m, blo(v.z), acc[4]);
  acc[5] = fmaf(m, bhi(v.z), acc[5]);
  acc[6] = fmaf(m, blo(v.w), acc[6]);
  acc[7] = fmaf(m, bhi(v.w), acc[7]);
}

__global__ __launch_bounds__(256) void k_agg_relu_proj_ell(
    const uint4* __restrict__ tpb4, const float* __restrict__ b,
    const float* __restrict__ w2l, const int* __restrict__ cur,
    const int* __restrict__ col, float* __restrict__ s_out) {
  int wid = threadIdx.x >> 6;
  int lane = threadIdx.x & 63;
  int d = blockIdx.x * 4 + wid;
  int il = lane & 7, g = lane >> 3;

  float acc[16];
#pragma unroll
  for (int j = 0; j < 16; ++j) acc[j] = 0.f;

  int degd = cur[d];
  int deg = min(degd, ELLW);
  int base = d * ELLW;
  for (int e = g; e < deg; e += 8) {
    int s = col[base + e];
    float ds = rsqrtf(1.0f + (float)cur[s]);
    uint4 v0 = tpb4[(size_t)s * 16 + il * 2];
    uint4 v1 = tpb4[(size_t)s * 16 + il * 2 + 1];
    acc8m(acc, v0, ds);
    acc8m(acc + 8, v1, ds);
  }
#pragma unroll
  for (int j = 0; j < 16; ++j) {
    acc[j] += __shfl_xor(acc[j], 8, 64);
    acc[j] += __shfl_xor(acc[j], 16, 64);
    acc[j] += __shfl_xor(acc[j], 32, 64);
  }
  float dv = rsqrtf(1.0f + (float)degd);
  // self loop
  uint4 s0 = tpb4[(size_t)d * 16 + il * 2];
  uint4 s1 = tpb4[(size_t)d * 16 + il * 2 + 1];
  acc8m(acc, s0, dv);
  acc8m(acc + 8, s1, dv);

  float p = 0.f;
#pragma unroll
  for (int q = 0; q < 4; ++q) {
    float4 bb = ((const float4*)b)[il * 4 + q];
    float4 ww = ((const float4*)w2l)[il * 4 + q];
    p = fmaf(fmaxf(fmaf(dv, acc[q * 4 + 0], bb.x), 0.f), ww.x, p);
    p = fmaf(fmaxf(fmaf(dv, acc[q * 4 + 1], bb.y), 0.f), ww.y, p);
    p = fmaf(fmaxf(fmaf(dv, acc[q * 4 + 2], bb.z), 0.f), ww.z, p);
    p = fmaf(fmaxf(fmaf(dv, acc[q * 4 + 3], bb.w), 0.f), ww.w, p);
  }
  // reduce across il (groups already merged)
  p += __shfl_xor(p, 1, 64);
  p += __shfl_xor(p, 2, 64);
  p += __shfl_xor(p, 4, 64);
  if (lane == 0) s_out[d] = dv * p;
}

// ---------------- Layer-2 scalar aggregate + sigmoid (ELL, inline dinv) ------

__global__ __launch_bounds__(256) void k_agg_scalar_ell(
    const float* __restrict__ s, const float* __restrict__ c0b,
    const int* __restrict__ cur, const int* __restrict__ col,
    float* __restrict__ out) {
  int wid = threadIdx.x >> 6;
  int lane = threadIdx.x & 63;
  int q = lane & 15;
  int d = blockIdx.x * 16 + wid * 4 + (lane >> 4);

  int degd = cur[d];
  int deg = min(degd, ELLW);
  int base = d * ELLW;
  float tot = 0.f;
  for (int e = q; e < deg; e += 16) tot += s[col[base + e]];
  tot += __shfl_xor(tot, 1, 64);
  tot += __shfl_xor(tot, 2, 64);
  tot += __shfl_xor(tot, 4, 64);
  tot += __shfl_xor(tot, 8, 64);
  if (q == 0) {
    float dv = rsqrtf(1.0f + (float)degd);
    float z = dv * (tot + s[d]) + c0b[0];
    out[d] = 1.f / (1.f + expf(-z));
  }
}

// ---------------- launch ----------------

extern "C" void kernel_launch(void* const* d_in, const int* in_sizes, int n_in,
                              void* d_out, int out_size, void* d_ws, size_t ws_size,
                              hipStream_t stream) {
  const float* x = (const float*)d_in[0];
  const int* ei = (const int*)d_in[1];   // harness passes integer inputs as int32
  const float* W1 = (const float*)d_in[2];
  const float* b1 = (const float*)d_in[3];
  const float* W2 = (const float*)d_in[4];
  const float* b2 = (const float*)d_in[5];
  const float* Wl = (const float*)d_in[6];
  const float* bl = (const float*)d_in[7];
  float* out = (float*)d_out;

  char* ws = (char*)d_ws;
  size_t off = 0;
  auto alloc = [&](size_t bytes) -> char* {
    char* p = ws + off;
    off = (off + bytes + 255) & ~(size_t)255;
    return p;
  };
  int* cur = (int*)alloc(NN * sizeof(int));
  int* colell = (int*)alloc((size_t)NN * ELLW * sizeof(int));  // 12.8 MB
  unsigned short* Wt1 = (unsigned short*)alloc(DD * DD * 2);
  float* w2l = (float*)alloc(DD * sizeof(float));
  float* c0b = (float*)alloc(sizeof(float));
  unsigned short* tpb = (unsigned short*)alloc((size_t)NPAD * DD * 2);
  float* sbuf = (float*)alloc(NN * sizeof(float));
  (void)ws_size;

  hipMemsetAsync(cur, 0, NN * sizeof(int), stream);
  // prep weights (Wt1 transpose + w2l fusion)
  k_prep_w<<<65, 256, 0, stream>>>(W1, W2, b2, Wl, bl, Wt1, w2l, c0b);

  // fused: GEMM (unscaled tp, LDS-free) + ELL scatter
  k_fused<<<NBG + 2048, 256, 0, stream>>>(x, Wt1, tpb, ei, cur, colell);

  // layer 1: aggregate+relu+projection (per-edge dinv inline)
  k_agg_relu_proj_ell<<<NN / 4, 256, 0, stream>>>((const uint4*)tpb, b1, w2l,
                                                  cur, colell, sbuf);
  // layer 2 + head: scalar aggregate + sigmoid
  k_agg_scalar_ell<<<(NN + 15) / 16, 256, 0, stream>>>(sbuf, c0b, cur, colell, out);
}

// Round 17
// 117.646 us; speedup vs baseline: 1.0111x; 1.0111x over previous
//
#include <hip/hip_runtime.h>
#include <math.h>

#define NN 50000
#define NE 800000
#define DD 128
#define NPAD 50048   // 782 * 64, GEMM row padding
#define NSLICE 6256  // ceil(NN/8) — dst-slice per XCD group
#define ELLW 64      // ELL row stride; P(deg>64) ~ 1e-15 for Poisson(16)

typedef __attribute__((ext_vector_type(8))) short bf16x8;
typedef __attribute__((ext_vector_type(4))) float f32x4;

__device__ __forceinline__ int clampN(int v) {
  return v < 0 ? 0 : (v >= NN ? NN - 1 : v);
}

__device__ __forceinline__ unsigned short f2b(float f) {
  union { float f; unsigned int u; } x; x.f = f;
  unsigned int u = x.u;
  u += 0x7fffu + ((u >> 16) & 1u);   // round-to-nearest-even
  return (unsigned short)(u >> 16);
}

__device__ __forceinline__ float blo(unsigned int v) {
  union { unsigned int u; float f; } a; a.u = v << 16; return a.f;
}
__device__ __forceinline__ float bhi(unsigned int v) {
  union { unsigned int u; float f; } a; a.u = v & 0xffff0000u; return a.f;
}

// ---------------- prep: Wt1 transpose-to-bf16 + fused head weights ----------------

__global__ __launch_bounds__(256) void k_prep_w(
    const float* __restrict__ W1, const float* __restrict__ W2,
    const float* __restrict__ b2, const float* __restrict__ Wl,
    const float* __restrict__ bl, unsigned short* __restrict__ Wt1,
    float* __restrict__ w2l, float* __restrict__ c0b) {
  __shared__ float part[2];
  if (blockIdx.x < 64) {
    int i = blockIdx.x * 256 + threadIdx.x;   // < 16384
    int n = i >> 7, k = i & 127;
    Wt1[i] = f2b(W1[k * DD + n]);
  } else if (threadIdx.x < DD) {
    int k = threadIdx.x;
    float acc = 0.f;
    for (int c = 0; c < DD; ++c) acc += W2[k * DD + c] * Wl[c];
    w2l[k] = acc;
    float pc = b2[k] * Wl[k];
#pragma unroll
    for (int off = 32; off > 0; off >>= 1) pc += __shfl_down(pc, off, 64);
    if ((k & 63) == 0) part[k >> 6] = pc;
    __syncthreads();
    if (k == 0) c0b[0] = part[0] + part[1] + bl[0];
  }
}

// ---------------- ELL scatter v4: int4-batched, XCD-sharded ----------------
// Each thread loads 4 consecutive (src,dst) pairs via two int4 loads, then
// runs 4 INDEPENDENT match/atomic/store units -> 4x fewer dependent waits.

__device__ __forceinline__ void scat1(int d, int s, int lo, int hi,
                                      int* __restrict__ cur, int* __restrict__ col) {
  d = clampN(d);
  if (d >= lo && d < hi) {
    int pos = atomicAdd(&cur[d], 1);
    if (pos < ELLW) col[d * ELLW + pos] = clampN(s);  // cap for memory safety
  }
}

__global__ __launch_bounds__(256) void k_scatter4(
    const int4* __restrict__ src4, const int4* __restrict__ dst4,
    int* __restrict__ cur, int* __restrict__ col) {
  int g = blockIdx.x & 7;            // physical XCD (round-robin dispatch)
  int blk = blockIdx.x >> 3;         // 0..255
  int lo = g * NSLICE;
  int hi = min(lo + NSLICE, NN);
  const int n4 = NE / 4;             // 200000
  for (int i = blk * 256 + threadIdx.x; i < n4; i += 256 * 256) {
    int4 d4 = dst4[i];
    int4 s4 = src4[i];
    scat1(d4.x, s4.x, lo, hi, cur, col);
    scat1(d4.y, s4.y, lo, hi, cur, col);
    scat1(d4.z, s4.z, lo, hi, cur, col);
    scat1(d4.w, s4.w, lo, hi, cur, col);
  }
}

// ---------------- MFMA GEMM (LDS version, unscaled output) ----------------

__global__ __launch_bounds__(256) void k_gemm_f32(
    const float* __restrict__ x, const unsigned short* __restrict__ Wt,
    unsigned short* __restrict__ outb) {
  __shared__ char lds[16384 + 32768];
  char* Al = lds;            // 64 rows x 256 B (bf16)
  char* Wl = lds + 16384;    // 128 rows x 256 B

  const int tid = threadIdx.x;
  const int row0 = blockIdx.x * 64;

  {  // stage A tile from f32, convert to bf16, swizzled 8B writes
    const float4* src = (const float4*)x;
#pragma unroll
    for (int kk = 0; kk < 8; ++kk) {
      int idx = tid + kk * 256;          // < 2048
      int r = idx >> 5;                  // row in tile (32 float4 per row)
      int c4 = idx & 31;
      float4 v = make_float4(0.f, 0.f, 0.f, 0.f);
      if (row0 + r < NN) v = src[(size_t)(row0 + r) * 32 + c4];
      ushort4 u;
      u.x = f2b(v.x); u.y = f2b(v.y); u.z = f2b(v.z); u.w = f2b(v.w);
      int bo = r * 256 + c4 * 8;
      *(ushort4*)(Al + (bo ^ ((r & 7) << 4))) = u;   // XOR hits bits 4-6 only
    }
  }
  {  // stage Wt (32 KB), swizzled
    const uint4* src = (const uint4*)Wt;
    for (int idx = tid; idx < 2048; idx += 256) {
      int bo = idx * 16;
      int r = bo >> 8;
      *(uint4*)(Wl + (bo ^ ((r & 7) << 4))) = src[idx];
    }
  }
  __syncthreads();

  const int w = tid >> 6, lane = tid & 63;
  const int lr = lane & 15, lk = lane >> 4;

  bf16x8 af[4];
  {
    int ar = w * 16 + lr;
    int base = ar * 256 + lk * 16;
    int swz = (ar & 7) << 4;
#pragma unroll
    for (int k4 = 0; k4 < 4; ++k4)
      af[k4] = *(const bf16x8*)(Al + ((base + k4 * 64) ^ swz));
  }

  f32x4 accs[8];
#pragma unroll
  for (int n = 0; n < 8; ++n) {
    f32x4 acc = {0.f, 0.f, 0.f, 0.f};
    int br = n * 16 + lr;
    int bbase = br * 256 + lk * 16;
    int bswz = (br & 7) << 4;
#pragma unroll
    for (int k4 = 0; k4 < 4; ++k4) {
      bf16x8 bf = *(const bf16x8*)(Wl + ((bbase + k4 * 64) ^ bswz));
      acc = __builtin_amdgcn_mfma_f32_16x16x32_bf16(af[k4], bf, acc, 0, 0, 0);
    }
    accs[n] = acc;
  }

#pragma unroll
  for (int r = 0; r < 4; ++r) {
    int grow = row0 + w * 16 + lk * 4 + r;
    if (grow < NN) {
#pragma unroll
      for (int n = 0; n < 8; ++n)
        outb[(size_t)grow * DD + n * 16 + lr] = f2b(accs[n][r]);  // UNSCALED
    }
  }
}

// ---------------- Layer-1 aggregate + relu + w2l projection (ELL, inline dinv) ----

__device__ __forceinline__ void acc8m(float* acc, uint4 v, float m) {
  acc[0] = fmaf(m, blo(v.x), acc[0]);
  acc[1] = fmaf(m, bhi(v.x), acc[1]);
  acc[2] = fmaf(m, blo(v.y), acc[2]);
  acc[3] = fmaf(m, bhi(v.y), acc[3]);
  acc[4] = fmaf(m, blo(v.z), acc[4]);
  acc[5] = fmaf(m, bhi(v.z), acc[5]);
  acc[6] = fmaf(m, blo(v.w), acc[6]);
  acc[7] = fmaf(m, bhi(v.w), acc[7]);
}

__global__ __launch_bounds__(256) void k_agg_relu_proj_ell(
    const uint4* __restrict__ tpb4, const float* __restrict__ b,
    const float* __restrict__ w2l, const int* __restrict__ cur,
    const int* __restrict__ col, float* __restrict__ s_out) {
  int wid = threadIdx.x >> 6;
  int lane = threadIdx.x & 63;
  int d = blockIdx.x * 4 + wid;
  int il = lane & 7, g = lane >> 3;

  float acc[16];
#pragma unroll
  for (int j = 0; j < 16; ++j) acc[j] = 0.f;

  int degd = cur[d];
  int deg = min(degd, ELLW);
  int base = d * ELLW;
  for (int e = g; e < deg; e += 8) {
    int s = col[base + e];
    float ds = rsqrtf(1.0f + (float)cur[s]);
    uint4 v0 = tpb4[(size_t)s * 16 + il * 2];
    uint4 v1 = tpb4[(size_t)s * 16 + il * 2 + 1];
    acc8m(acc, v0, ds);
    acc8m(acc + 8, v1, ds);
  }
#pragma unroll
  for (int j = 0; j < 16; ++j) {
    acc[j] += __shfl_xor(acc[j], 8, 64);
    acc[j] += __shfl_xor(acc[j], 16, 64);
    acc[j] += __shfl_xor(acc[j], 32, 64);
  }
  float dv = rsqrtf(1.0f + (float)degd);
  // self loop
  uint4 s0 = tpb4[(size_t)d * 16 + il * 2];
  uint4 s1 = tpb4[(size_t)d * 16 + il * 2 + 1];
  acc8m(acc, s0, dv);
  acc8m(acc + 8, s1, dv);

  float p = 0.f;
#pragma unroll
  for (int q = 0; q < 4; ++q) {
    float4 bb = ((const float4*)b)[il * 4 + q];
    float4 ww = ((const float4*)w2l)[il * 4 + q];
    p = fmaf(fmaxf(fmaf(dv, acc[q * 4 + 0], bb.x), 0.f), ww.x, p);
    p = fmaf(fmaxf(fmaf(dv, acc[q * 4 + 1], bb.y), 0.f), ww.y, p);
    p = fmaf(fmaxf(fmaf(dv, acc[q * 4 + 2], bb.z), 0.f), ww.z, p);
    p = fmaf(fmaxf(fmaf(dv, acc[q * 4 + 3], bb.w), 0.f), ww.w, p);
  }
  // reduce across il (groups already merged)
  p += __shfl_xor(p, 1, 64);
  p += __shfl_xor(p, 2, 64);
  p += __shfl_xor(p, 4, 64);
  if (lane == 0) s_out[d] = dv * p;
}

// ---------------- Layer-2 scalar aggregate + sigmoid (ELL, inline dinv) ------

__global__ __launch_bounds__(256) void k_agg_scalar_ell(
    const float* __restrict__ s, const float* __restrict__ c0b,
    const int* __restrict__ cur, const int* __restrict__ col,
    float* __restrict__ out) {
  int wid = threadIdx.x >> 6;
  int lane = threadIdx.x & 63;
  int q = lane & 15;
  int d = blockIdx.x * 16 + wid * 4 + (lane >> 4);

  int degd = cur[d];
  int deg = min(degd, ELLW);
  int base = d * ELLW;
  float tot = 0.f;
  for (int e = q; e < deg; e += 16) tot += s[col[base + e]];
  tot += __shfl_xor(tot, 1, 64);
  tot += __shfl_xor(tot, 2, 64);
  tot += __shfl_xor(tot, 4, 64);
  tot += __shfl_xor(tot, 8, 64);
  if (q == 0) {
    float dv = rsqrtf(1.0f + (float)degd);
    float z = dv * (tot + s[d]) + c0b[0];
    out[d] = 1.f / (1.f + expf(-z));
  }
}

// ---------------- launch ----------------

extern "C" void kernel_launch(void* const* d_in, const int* in_sizes, int n_in,
                              void* d_out, int out_size, void* d_ws, size_t ws_size,
                              hipStream_t stream) {
  const float* x = (const float*)d_in[0];
  const int* ei = (const int*)d_in[1];   // harness passes integer inputs as int32
  const float* W1 = (const float*)d_in[2];
  const float* b1 = (const float*)d_in[3];
  const float* W2 = (const float*)d_in[4];
  const float* b2 = (const float*)d_in[5];
  const float* Wl = (const float*)d_in[6];
  const float* bl = (const float*)d_in[7];
  float* out = (float*)d_out;

  char* ws = (char*)d_ws;
  size_t off = 0;
  auto alloc = [&](size_t bytes) -> char* {
    char* p = ws + off;
    off = (off + bytes + 255) & ~(size_t)255;
    return p;
  };
  int* cur = (int*)alloc(NN * sizeof(int));
  int* colell = (int*)alloc((size_t)NN * ELLW * sizeof(int));  // 12.8 MB
  unsigned short* Wt1 = (unsigned short*)alloc(DD * DD * 2);
  float* w2l = (float*)alloc(DD * sizeof(float));
  float* c0b = (float*)alloc(sizeof(float));
  unsigned short* tpb = (unsigned short*)alloc((size_t)NPAD * DD * 2);
  float* sbuf = (float*)alloc(NN * sizeof(float));
  (void)ws_size;

  hipMemsetAsync(cur, 0, NN * sizeof(int), stream);
  // prep weights (Wt1 transpose + w2l fusion)
  k_prep_w<<<65, 256, 0, stream>>>(W1, W2, b2, Wl, bl, Wt1, w2l, c0b);

  // ELL scatter (int4-batched, XCD-sharded)
  k_scatter4<<<2048, 256, 0, stream>>>((const int4*)ei, (const int4*)(ei + NE),
                                       cur, colell);

  // layer-1 GEMM (unscaled tp)
  k_gemm_f32<<<NPAD / 64, 256, 0, stream>>>(x, Wt1, tpb);

  // layer 1: aggregate+relu+projection (per-edge dinv inline)
  k_agg_relu_proj_ell<<<NN / 4, 256, 0, stream>>>((const uint4*)tpb, b1, w2l,
                                                  cur, colell, sbuf);
  // layer 2 + head: scalar aggregate + sigmoid
  k_agg_scalar_ell<<<(NN + 15) / 16, 256, 0, stream>>>(sbuf, c0b, cur, colell, out);
}